// Round 12
// baseline (107.679 us; speedup 1.0000x reference)
//
#include <hip/hip_runtime.h>
#include <hip/hip_bf16.h>

// out[t,e] = W[e, idx[t]] + bias[e],  t = 0..8191
// idx: [8192] int32, W: [512,32000] fp32 row-major, bias: [512], out: [8192,512]
//
// Pipelined W-stationary kernel. Each block owns vocab chunk cx (512 cols)
// and FOUR 16-row embed tiles (ey = blockIdx.y*4 .. +3), double-buffered:
//   prologue: issue DMA(tile0); scan idx with ballot-compaction (no atomics,
//             no init barrier -> scan truly overlaps DMA); __syncthreads
//   steady:   issue DMA(t+1) -> s_waitcnt vmcnt(8) (counted: tile t drained,
//             t+1 in flight) -> s_barrier -> scatter tile t -> lgkm+barrier
// W read exactly once sequentially; scan redundancy 4x lower (504 scans).

constexpr int VOCAB  = 32000;
constexpr int EMBED  = 512;
constexpr int VSHIFT = 9;
constexpr int VC     = 1 << VSHIFT;            // 512
constexpr int NCHUNK = (VOCAB + VC - 1) / VC;  // 63 (last chunk: 256 cols)
constexpr int ET     = 16;                     // rows per tile
constexpr int PAD    = 516;                    // LDS row pitch (floats)
constexpr int WSEG   = 512;                    // per-wave list segment (4 waves)

__global__ __launch_bounds__(256) void fused_embed_pipe(
    const int* __restrict__ idx,
    const float* __restrict__ W,
    const float* __restrict__ bias,
    float* __restrict__ out,
    int ntok)
{
    __shared__ float buf[2 * ET * PAD];   // two 33KB tile buffers
    __shared__ int   list[4 * WSEG];      // per-wave segments, (t<<9)|vl
    __shared__ int   wcnts[4];

    const int cx   = blockIdx.x;                 // vocab chunk
    const int c0   = cx << VSHIFT;
    const int e0g  = blockIdx.y << 6;            // this block's 64 embed rows
    const int tid  = threadIdx.x;
    const int wv   = tid >> 6;                   // wave 0..3
    const int lane = tid & 63;
    const int j    = tid & 15;                   // embed offset in tile
    const int rowb = j * PAD;

    const int cols = min(VC, VOCAB - c0);        // 512, or 256 for cx=62
    const int cpr  = cols >> 8;                  // 2 or 1
    float* bA = buf;
    float* bB = buf + ET * PAD;

    // Issue one 16x512 tile as 32 wave-chunks (8 per wave, 1KB each).
    // For the short last chunk (cpr==1) the h==1 half re-reads h==0's source
    // (stays in-bounds); its LDS copy lands at +256 floats and is never read
    // since vl < 256 there.
    auto issue_tile = [&](float* dst, int e0t) {
        for (int c = wv; c < 32; c += 4) {
            int r    = c >> 1;
            int h    = c & 1;
            int hoff = (h & (cpr - 1)) << 8;     // 0/256, forced 0 when cpr==1
            const float* src = W + (size_t)(e0t + r) * VOCAB + c0 + hoff + (lane << 2);
            __builtin_amdgcn_global_load_lds(
                (const __attribute__((address_space(1))) void*)src,
                (__attribute__((address_space(3))) void*)(dst + r * PAD + (h << 8)),
                16, 0, 0);
        }
    };

    auto scatter_tile = [&](const float* b, float bv, int e0t) {
        for (int w = 0; w < 4; ++w) {
            int nw = wcnts[w];
            const int* seg = list + w * WSEG;
            for (int k = tid >> 4; k < nw; k += 16) {
                int e   = seg[k];                // LDS broadcast per 16-lane group
                int tok = e >> VSHIFT;
                int vl  = e & (VC - 1);
                float val = b[rowb + vl] + bv;
                __builtin_nontemporal_store(val, &out[(size_t)tok * EMBED + e0t + j]);
            }
        }
    };

    // ---- Prologue: DMA tile0, then scan (overlaps DMA; no barriers) ----
    issue_tile(bA, e0g);

    const float bv0 = bias[e0g + j];
    const float bv1 = bias[e0g + 16 + j];
    const float bv2 = bias[e0g + 32 + j];
    const float bv3 = bias[e0g + 48 + j];

    // Ballot-compacted scan: each wave owns list[wv*WSEG ..]. No atomics.
    {
        int wbase = 0;
        const int n4 = ntok >> 2;
        const int4* idx4 = (const int4*)idx;
        for (int q = tid; q < n4; q += 256) {
            int4 v = idx4[q];
            int t = q << 2;
            unsigned long long lt = (1ull << lane) - 1;
            #pragma unroll
            for (int s = 0; s < 4; ++s) {
                int vi = (s == 0) ? v.x : (s == 1) ? v.y : (s == 2) ? v.z : v.w;
                bool m = ((vi >> VSHIFT) == cx);
                unsigned long long bm = __ballot(m);
                if (m) {
                    int p = wbase + __popcll(bm & lt);
                    if (p < WSEG) list[wv * WSEG + p] = ((t + s) << VSHIFT) | (vi & (VC - 1));
                }
                wbase += __popcll(bm);
            }
        }
        if (lane == 0) wcnts[wv] = min(wbase, WSEG);
    }

    __syncthreads();   // drains DMA0 + scan loads + list writes; all ready

    // ---- Pipelined tiles: DMA(t+1) overlaps scatter(t) ----
    issue_tile(bB, e0g + 16);                    // tile1
    scatter_tile(bA, bv0, e0g);                  // tile0
    asm volatile("s_waitcnt lgkmcnt(0)" ::: "memory");
    __builtin_amdgcn_s_barrier();                // bA free

    issue_tile(bA, e0g + 32);                    // tile2
    asm volatile("s_waitcnt vmcnt(8)" ::: "memory");   // tile1 landed (tile2 in flight)
    __builtin_amdgcn_s_barrier();
    scatter_tile(bB, bv1, e0g + 16);             // tile1
    asm volatile("s_waitcnt lgkmcnt(0)" ::: "memory");
    __builtin_amdgcn_s_barrier();                // bB free

    issue_tile(bB, e0g + 48);                    // tile3
    asm volatile("s_waitcnt vmcnt(8)" ::: "memory");   // tile2 landed
    __builtin_amdgcn_s_barrier();
    scatter_tile(bA, bv2, e0g + 32);             // tile2

    asm volatile("s_waitcnt vmcnt(0)" ::: "memory");   // tile3 landed
    __builtin_amdgcn_s_barrier();
    scatter_tile(bB, bv3, e0g + 48);             // tile3
}

extern "C" void kernel_launch(void* const* d_in, const int* in_sizes, int n_in,
                              void* d_out, int out_size, void* d_ws, size_t ws_size,
                              hipStream_t stream) {
    const int*   idx  = (const int*)d_in[0];   // [8192]
    const float* W    = (const float*)d_in[1]; // [512,32000]
    const float* bias = (const float*)d_in[2]; // [512]
    float* out = (float*)d_out;                // [8192,512]

    int ntok = in_sizes[0];

    dim3 grid(NCHUNK, EMBED / 64);             // 63 x 8 = 504 blocks, all resident
    fused_embed_pipe<<<grid, 256, 0, stream>>>(idx, W, bias, out, ntok);
}